// Round 8
// baseline (197.741 us; speedup 1.0000x reference)
//
#include <hip/hip_runtime.h>

#define S_    2048
#define N_    16
#define OBS_  8
#define PRED_ 12
#define B_    (S_*N_)
#define SCN_  4     // scenes per block = 2 waves x 2 scenes/wave

typedef __attribute__((ext_vector_type(8))) short short8;
typedef __attribute__((ext_vector_type(4))) float floatx4;
typedef __attribute__((ext_vector_type(4))) unsigned uintx4;
typedef unsigned short ushort_t;

__device__ __forceinline__ float sigmf(float x) { return __builtin_amdgcn_rcpf(1.0f + __expf(-x)); }
__device__ __forceinline__ float tanhx(float x) { return fmaf(-2.0f, __builtin_amdgcn_rcpf(1.0f + __expf(2.0f*x)), 1.0f); }
// f32 -> bf16 round-half-up: bits+0x8000, truncate. <=0.5 ulp like RNE (ties differ only).
__device__ __forceinline__ unsigned bfhi(float f) {
  return __builtin_bit_cast(unsigned, f) + 0x8000u;
}
__device__ __forceinline__ unsigned pack2bf(float lo, float hi) {
  return __builtin_amdgcn_perm(bfhi(hi), bfhi(lo), 0x07060302);  // [hi.b3,hi.b2,lo.b3,lo.b2]
}
__device__ __forceinline__ ushort_t f2bf1(float f) { return (ushort_t)(bfhi(f) >> 16); }
__device__ __forceinline__ float rlanef(float v, int lane) {
  return __builtin_bit_cast(float, __builtin_amdgcn_readlane(__builtin_bit_cast(int, v), lane));
}
__device__ __forceinline__ unsigned shflu(unsigned v, int src) {
  return (unsigned)__shfl((int)v, src, 64);
}
__device__ __forceinline__ unsigned shflxu(unsigned v, int m) {
  return (unsigned)__shfl_xor((int)v, m, 64);
}

// R21: two scenes per wave (static dual-chain ILP). R20 post-mortem: invented
// permlane semantics -> absmax 4.75; ALL R20 routing reverted to R19's proven
// shfl/readlane primitives. R19 model refined: wall ~11.3k cy/step, VALU issue
// ~6k/SIMD -> SIMD idle ~47% with both waves stalled; instruction count is
// near-irreducible (refrag fma = unique work), so the lever is FILLING the
// idle: each wave now owns TWO independent scenes, phases interleaved in
// source (A,B,A,B...) so the scheduler fills chain-A latency (MFMA/DS/trans)
// with chain-B VALU ops. Waves 2048->1024 (1/SIMD, 4/CU) — same scenes/SIMD,
// static interleave instead of dynamic; launch_bounds(128,1) unlocks 512 VGPR.
// Every per-scene instruction sequence is byte-identical to R19 ->
// absmax MUST stay exactly 0.03125 (tripwire; else transcription bug).
// Tripwires: FETCH/WRITE balloon or VGPR>~440 -> scratch spill -> revert R19.
extern "C" __global__ __launch_bounds__(128, 1) void traj_ar_kernel(
    const float* __restrict__ traj_rel, const float* __restrict__ obs_pos,
    const int*  __restrict__ nei,       const float* __restrict__ noise,
    const float* __restrict__ eeW, const float* __restrict__ eeb,
    const float* __restrict__ eWi, const float* __restrict__ eWh, const float* __restrict__ eb,
    const float* __restrict__ diW, const float* __restrict__ dib,
    const float* __restrict__ dWi, const float* __restrict__ dWh, const float* __restrict__ db,
    const float* __restrict__ prW, const float* __restrict__ prb,
    const float* __restrict__ mW,  const float* __restrict__ mb,
    const float* __restrict__ oW,  const float* __restrict__ ob,
    float* __restrict__ out)
{
  // per-scene (wave-private) state only — nothing cross-wave, zero barriers
  __shared__ __align__(16) float h_s[SCN_][256];       // f32 h, phase-5 input
  __shared__ __align__(16) float ctx_s[SCN_][256];     // f32 ctx, phase-5 input
  __shared__ __align__(16) ushort_t ctx_bf[SCN_][384]; // bf16 ctx, phase-1 B input
  __shared__            unsigned sm_s[SCN_][16];

  const int tid = threadIdx.x;
  const int w  = tid >> 6;              // wave index
  const int l  = tid & 63;
  const int lq = l >> 4;                // quad (16-lane row) within wave
  const int lc = l & 15;                // col within wave (agent / unit-col)
  const int u0 = lq*4;                  // this lane's unit base
  const bool hi_half = (lq >= 2);       // lanes 32..63
  const int slA = w*2, slB = w*2 + 1;   // this wave's two scene slots
  const int sA = blockIdx.x*SCN_ + slA; // scene ids
  const int sB = sA + 1;
  // fragment-routing source lanes (R19-proven): lane's b128 e/h fragment =
  // {ep.x,ep.y} of lane esrc0 then lane esrc1
  const int esrc0 = (lq & 1)*32 + lc;
  const int esrc1 = esrc0 + 16;

  // ---- per-wave scene init ----
  { unsigned* cz = (unsigned*)ctx_bf[slA]; cz[l]=0; cz[64+l]=0; cz[128+l]=0; }
  { unsigned* cz = (unsigned*)ctx_bf[slB]; cz[l]=0; cz[64+l]=0; cz[128+l]=0; }

  float POSXA = obs_pos[((OBS_-1)*B_ + sA*N_ + lc)*2 + 0];
  float POSYA = obs_pos[((OBS_-1)*B_ + sA*N_ + lc)*2 + 1];
  float POSXB = obs_pos[((OBS_-1)*B_ + sB*N_ + lc)*2 + 0];
  float POSYB = obs_pos[((OBS_-1)*B_ + sB*N_ + lc)*2 + 1];
  unsigned prevuA, prevuB;
  {
    float px = traj_rel[((OBS_-1)*B_ + sA*N_ + lc)*2 + 0];
    float py = traj_rel[((OBS_-1)*B_ + sA*N_ + lc)*2 + 1];
    prevuA = pack2bf(px, py);
  }
  {
    float px = traj_rel[((OBS_-1)*B_ + sB*N_ + lc)*2 + 0];
    float py = traj_rel[((OBS_-1)*B_ + sB*N_ + lc)*2 + 1];
    prevuB = pack2bf(px, py);
  }
  // time-invariant neighbor masks (init-only; same-wave LDS, in-order)
  #define MK_MASK(sS, slS) {                                                \
    const int a_ = l >> 2, nb_ = (l & 3)*4;                                 \
    const int4 nv_ = *(const int4*)&nei[((sS)*N_ + a_)*N_ + nb_];           \
    unsigned bits_ = 0;                                                     \
    bits_ |= (nv_.x > 0) ? (1u << (nb_+0)) : 0u;                            \
    bits_ |= (nv_.y > 0) ? (1u << (nb_+1)) : 0u;                            \
    bits_ |= (nv_.z > 0) ? (1u << (nb_+2)) : 0u;                            \
    bits_ |= (nv_.w > 0) ? (1u << (nb_+3)) : 0u;                            \
    bits_ |= __shfl_xor(bits_, 1, 64);                                      \
    bits_ |= __shfl_xor(bits_, 2, 64);                                      \
    if ((l & 3) == 0) sm_s[slS][a_] = bits_;                                \
  }
  MK_MASK(sA, slA)
  MK_MASK(sB, slB)

  // ---- shared weights (identical for both scenes) ----
  short8 bfrag;
  {
    uintx4 bw;
    #pragma unroll
    for (int p = 0; p < 4; ++p)
      bw[p] = pack2bf(mW[(8*lq + 2*p)*16 + lc], mW[(8*lq + 2*p + 1)*16 + lc]);
    bfrag = __builtin_bit_cast(short8, bw);
  }
  const float bm = mb[lc];

  float pWx[8], pWy[8], pB[8];
  {
    const int wu0 = (lq & 1) * 8;
    #pragma unroll
    for (int j = 0; j < 8; ++j) {
      pWx[j] = prW[wu0 + j];
      pWy[j] = prW[16 + wu0 + j];
      pB[j]  = prb[wu0 + j];
    }
  }

  float oWc[16];
  #pragma unroll
  for (int m = 0; m < 16; ++m) oWc[m] = oW[m*4 + lq];
  const float obia = ob[lq];

  float ew0[4], ew1[4], ebv[4];
  #pragma unroll
  for (int r = 0; r < 4; ++r) {
    ew0[r] = eeW[u0+r]; ew1[r] = eeW[16+u0+r]; ebv[r] = eeb[u0+r];
  }

  const int row0 = (lq & 1) * 8;

  #define LOAD_GATE_FRAG(A, C, Wi_, Wh_, bias_, g) {                                      \
    const float* gsrc_ = (lq & 2) ? (Wh_) : (Wi_);                                        \
    uintx4 aw_;                                                                           \
    aw_[0] = pack2bf(gsrc_[(row0+0)*64 + (g)*16 + lc], gsrc_[(row0+1)*64 + (g)*16 + lc]); \
    aw_[1] = pack2bf(gsrc_[(row0+2)*64 + (g)*16 + lc], gsrc_[(row0+3)*64 + (g)*16 + lc]); \
    aw_[2] = pack2bf(gsrc_[(row0+4)*64 + (g)*16 + lc], gsrc_[(row0+5)*64 + (g)*16 + lc]); \
    aw_[3] = pack2bf(gsrc_[(row0+6)*64 + (g)*16 + lc], gsrc_[(row0+7)*64 + (g)*16 + lc]); \
    (A) = __builtin_bit_cast(short8, aw_);                                                \
    (C)[0] = (bias_)[(g)*16 + u0 + 0]; (C)[1] = (bias_)[(g)*16 + u0 + 1];                 \
    (C)[2] = (bias_)[(g)*16 + u0 + 2]; (C)[3] = (bias_)[(g)*16 + u0 + 3];                 \
  }

  short8 eA0, eA1, eA2, eA3; floatx4 eC0, eC1, eC2, eC3;
  LOAD_GATE_FRAG(eA0, eC0, eWi, eWh, eb, 0);
  LOAD_GATE_FRAG(eA1, eC1, eWi, eWh, eb, 1);
  LOAD_GATE_FRAG(eA2, eC2, eWi, eWh, eb, 2);
  LOAD_GATE_FRAG(eA3, eC3, eWi, eWh, eb, 3);

  #define LSTM_EW(C4, r, hv) {                                                        \
    float ig = sigmf(dI[r]), fg = sigmf(dF[r]), gv = tanhx(dG[r]), og = sigmf(dO[r]); \
    (C4)[r] = fg*(C4)[r] + ig*gv;                                                     \
    hv = og * tanhx((C4)[r]);                                                         \
  }

  // encoder step (R19-identical per scene): e via regs, fragments via shfl
  #define ENC_STEP(sS, C4, HF) {                                            \
    float2 x_ = xr2[t*B_ + (sS)*N_ + lc];                                   \
    float e0_ = fmaxf(fmaf(x_.y, ew1[0], fmaf(x_.x, ew0[0], ebv[0])), 0.0f);\
    float e1_ = fmaxf(fmaf(x_.y, ew1[1], fmaf(x_.x, ew0[1], ebv[1])), 0.0f);\
    float e2_ = fmaxf(fmaf(x_.y, ew1[2], fmaf(x_.x, ew0[2], ebv[2])), 0.0f);\
    float e3_ = fmaxf(fmaf(x_.y, ew1[3], fmaf(x_.x, ew0[3], ebv[3])), 0.0f);\
    uint2 ep_; ep_.x = pack2bf(e0_, e1_); ep_.y = pack2bf(e2_, e3_);        \
    uintx4 eu_;                                                             \
    eu_[0] = shflu(ep_.x, esrc0); eu_[1] = shflu(ep_.y, esrc0);             \
    eu_[2] = shflu(ep_.x, esrc1); eu_[3] = shflu(ep_.y, esrc1);             \
    uintx4 bu_ = (lq < 2) ? eu_ : (HF);                                     \
    short8 bfr_ = __builtin_bit_cast(short8, bu_);                          \
    floatx4 dI = __builtin_amdgcn_mfma_f32_16x16x32_bf16(eA0, bfr_, eC0, 0, 0, 0); \
    floatx4 dF = __builtin_amdgcn_mfma_f32_16x16x32_bf16(eA1, bfr_, eC1, 0, 0, 0); \
    floatx4 dG = __builtin_amdgcn_mfma_f32_16x16x32_bf16(eA2, bfr_, eC2, 0, 0, 0); \
    floatx4 dO = __builtin_amdgcn_mfma_f32_16x16x32_bf16(eA3, bfr_, eC3, 0, 0, 0); \
    float h40_, h41_, h42_, h43_;                                           \
    LSTM_EW(C4, 0, h40_); LSTM_EW(C4, 1, h41_);                             \
    LSTM_EW(C4, 2, h42_); LSTM_EW(C4, 3, h43_);                             \
    uint2 hp2_; hp2_.x = pack2bf(h40_, h41_); hp2_.y = pack2bf(h42_, h43_); \
    (HF)[0] = shflu(hp2_.x, esrc0); (HF)[1] = shflu(hp2_.y, esrc0);         \
    (HF)[2] = shflu(hp2_.x, esrc1); (HF)[3] = shflu(hp2_.y, esrc1);         \
  }

  // h fragments carried across steps; h0 = 0
  uintx4 hfA; hfA[0]=0; hfA[1]=0; hfA[2]=0; hfA[3]=0;
  uintx4 hfB; hfB[0]=0; hfB[1]=0; hfB[2]=0; hfB[3]=0;

  // ---- encoder: 8 LSTM steps x 2 scenes, interleaved, zero barriers ----
  floatx4 c4A = {0.0f,0.0f,0.0f,0.0f}, c4B = {0.0f,0.0f,0.0f,0.0f};
  const float2* xr2 = (const float2*)traj_rel;
  for (int t = 0; t < OBS_; ++t) {
    ENC_STEP(sA, c4A, hfA)
    ENC_STEP(sB, c4B, hfB)
  }

  // decoder gate A-frags (separate live range from encoder's)
  short8 dA0, dA1, dA2, dA3; floatx4 dC0, dC1, dC2, dC3;
  LOAD_GATE_FRAG(dA0, dC0, dWi, dWh, db, 0);
  LOAD_GATE_FRAG(dA1, dC1, dWi, dWh, db, 1);
  LOAD_GATE_FRAG(dA2, dC2, dWi, dWh, db, 2);
  LOAD_GATE_FRAG(dA3, dC3, dWi, dWh, db, 3);

  // dec-in A-fragment: kk 0..15 = ctx rows, 16,17 = prev rows, 18..31 zero-pad
  short8 diA; floatx4 diC;
  {
    uintx4 aw; aw[0]=0; aw[1]=0; aw[2]=0; aw[3]=0;
    if (lq < 2) {
      const int r0 = lq*8;
      #pragma unroll
      for (int p = 0; p < 4; ++p)
        aw[p] = pack2bf(diW[(r0+2*p)*16 + lc], diW[(r0+2*p+1)*16 + lc]);
    } else if (lq == 2) {
      aw[0] = pack2bf(diW[16*16 + lc], diW[17*16 + lc]);
    }
    diA = __builtin_bit_cast(short8, aw);
    #pragma unroll
    for (int r = 0; r < 4; ++r) diC[r] = dib[u0 + r];
  }

  // pool C-operands per scene, mask baked (time-invariant; full unroll)
  floatx4 cmA[16], cmB[16];
  #pragma unroll
  for (int tt = 0; tt < 16; ++tt) {
    const unsigned miA = sm_s[slA][tt];
    const unsigned miB = sm_s[slB][tt];
    #pragma unroll
    for (int r = 0; r < 4; ++r) {
      cmA[tt][r] = ((miA >> (u0 + r)) & 1u) ? bm : -1e9f;
      cmB[tt][r] = ((miB >> (u0 + r)) & 1u) ? bm : -1e9f;
    }
  }

  // R19-identical refrag: lanes<32 re(2pp), lanes>=32 re(2pp+1); F1 routed
  // down via proven shfl_xor(32). Bit-identical fma nesting + pack pairing.
  #define MK_REFRAG(PXs, PYs, pp, PX, PY, F0, F1) {                         \
    const int t0_ = 2*(pp), t1_ = 2*(pp)+1;                                 \
    float rx0_ = (PXs)[t0_] - (PX), ry0_ = (PYs)[t0_] - (PY);               \
    float rx1_ = (PXs)[t1_] - (PX), ry1_ = (PYs)[t1_] - (PY);               \
    float rx_ = hi_half ? rx1_ : rx0_;                                      \
    float ry_ = hi_half ? ry1_ : ry0_;                                      \
    float rr_[8];                                                           \
    _Pragma("unroll")                                                       \
    for (int j_ = 0; j_ < 8; ++j_)                                          \
      rr_[j_] = fmaxf(fmaf(ry_, pWy[j_], fmaf(rx_, pWx[j_], pB[j_])), 0.0f);\
    (F0)[0] = pack2bf(rr_[0], rr_[1]);                                      \
    (F0)[1] = pack2bf(rr_[2], rr_[3]);                                      \
    (F0)[2] = pack2bf(rr_[4], rr_[5]);                                      \
    (F0)[3] = pack2bf(rr_[6], rr_[7]);                                      \
    (F1)[0] = shflxu((F0)[0], 32);                                          \
    (F1)[1] = shflxu((F0)[1], 32);                                          \
    (F1)[2] = shflxu((F0)[2], 32);                                          \
    (F1)[3] = shflxu((F0)[3], 32);                                          \
  }

  // R19-identical pool tile (proven shfl_xor reduce, writer lq == tt&3)
  #define POOL_TILE(slS, CM, tt, FRAG, HF) {                                \
    short8 a_ = hi_half ? __builtin_bit_cast(short8, HF)                    \
                        : __builtin_bit_cast(short8, FRAG);                 \
    floatx4 d_ = __builtin_amdgcn_mfma_f32_16x16x32_bf16(a_, bfrag, (CM)[tt], 0, 0, 0); \
    float pm_ = fmaxf(fmaxf(d_[0], d_[1]), fmaxf(d_[2], d_[3]));            \
    pm_ = fmaxf(pm_, __shfl_xor(pm_, 16, 64));                              \
    pm_ = fmaxf(pm_, __shfl_xor(pm_, 32, 64));                              \
    if (lq == ((tt) & 3)) {                                                 \
      float cvv_ = fmaxf(pm_, 0.0f);                                        \
      ctx_s[slS][(tt)*16 + lc] = cvv_;                                      \
      ctx_bf[slS][(tt)*24 + lc] = f2bf1(cvv_);                              \
    }                                                                       \
  }

  #define PH1(slS, PREVU, EP) {                                             \
    short8 cv_ = *(const short8*)&ctx_bf[slS][lc*24 + (lq&1)*8];            \
    uintx4 pz_; pz_[0] = (PREVU); pz_[1]=0; pz_[2]=0; pz_[3]=0;             \
    short8 pv_ = __builtin_bit_cast(short8, pz_);                           \
    short8 zz_ = {0,0,0,0,0,0,0,0};                                         \
    short8 bf1_ = (lq < 2) ? cv_ : ((lq == 2) ? pv_ : zz_);                 \
    floatx4 d_ = __builtin_amdgcn_mfma_f32_16x16x32_bf16(diA, bf1_, diC, 0, 0, 0); \
    (EP).x = pack2bf(fmaxf(d_[0],0.0f), fmaxf(d_[1],0.0f));                 \
    (EP).y = pack2bf(fmaxf(d_[2],0.0f), fmaxf(d_[3],0.0f));                 \
  }

  #define PH2(slS, EP, C4, HF) {                                            \
    uintx4 eu_;                                                             \
    eu_[0] = shflu((EP).x, esrc0); eu_[1] = shflu((EP).y, esrc0);           \
    eu_[2] = shflu((EP).x, esrc1); eu_[3] = shflu((EP).y, esrc1);           \
    uintx4 bu_ = (lq < 2) ? eu_ : (HF);                                     \
    short8 bfr_ = __builtin_bit_cast(short8, bu_);                          \
    floatx4 dI = __builtin_amdgcn_mfma_f32_16x16x32_bf16(dA0, bfr_, dC0, 0, 0, 0); \
    floatx4 dF = __builtin_amdgcn_mfma_f32_16x16x32_bf16(dA1, bfr_, dC1, 0, 0, 0); \
    floatx4 dG = __builtin_amdgcn_mfma_f32_16x16x32_bf16(dA2, bfr_, dC2, 0, 0, 0); \
    floatx4 dO = __builtin_amdgcn_mfma_f32_16x16x32_bf16(dA3, bfr_, dC3, 0, 0, 0); \
    float h40_, h41_, h42_, h43_;                                           \
    LSTM_EW(C4, 0, h40_); LSTM_EW(C4, 1, h41_);                             \
    LSTM_EW(C4, 2, h42_); LSTM_EW(C4, 3, h43_);                             \
    uint2 hp2_; hp2_.x = pack2bf(h40_, h41_); hp2_.y = pack2bf(h42_, h43_); \
    (HF)[0] = shflu(hp2_.x, esrc0); (HF)[1] = shflu(hp2_.y, esrc0);         \
    (HF)[2] = shflu(hp2_.x, esrc1); (HF)[3] = shflu(hp2_.y, esrc1);         \
    floatx4 hv4_; hv4_[0]=h40_; hv4_[1]=h41_; hv4_[2]=h42_; hv4_[3]=h43_;   \
    *(floatx4*)&h_s[slS][lc*16 + u0] = hv4_;                                \
  }

  #define PH5(slS, sS, NZ, PX, PY, PREVU) {                                 \
    float acc_ = obia;                                                      \
    const floatx4* hp4_ = (const floatx4*)&h_s[slS][lc*16];                 \
    const floatx4* cx4_ = (const floatx4*)&ctx_s[slS][lc*16];               \
    _Pragma("unroll")                                                       \
    for (int mm_ = 0; mm_ < 4; ++mm_) {                                     \
      floatx4 hv_ = hp4_[mm_];                                              \
      floatx4 cv_ = cx4_[mm_];                                              \
      _Pragma("unroll")                                                     \
      for (int r_ = 0; r_ < 4; ++r_)                                        \
        acc_ = fmaf(hv_[r_]+cv_[r_], oWc[mm_*4+r_], acc_);                  \
    }                                                                       \
    float sc_ = __shfl_down(acc_, 32, 64);                                  \
    float mu_ = acc_;                                                       \
    float scale_ = fminf(fmaxf(sc_, -9.0f), 4.0f);                          \
    float sd_ = __expf(scale_);                                             \
    float pr_ = fmaf(sd_, (NZ), mu_);                                       \
    if (lq < 2) {                                                           \
      int o_ = (t*B_ + (sS)*N_ + lc)*2 + lq;                                \
      out[o_]          = pr_;                                               \
      out[MU_OFF + o_] = mu_;                                               \
      out[SD_OFF + o_] = sd_;                                               \
    }                                                                       \
    float prx_ = __shfl(pr_, lc, 64);                                       \
    float pry_ = __shfl(pr_, 16 + lc, 64);                                  \
    (PX) += prx_;                                                           \
    (PY) += pry_;                                                           \
    (PREVU) = pack2bf(prx_, pry_);                                          \
  }

  // ---- decoder: 12 AR steps x 2 scenes, phase-interleaved, zero barriers ----
  c4A = (floatx4){0.0f,0.0f,0.0f,0.0f};
  c4B = (floatx4){0.0f,0.0f,0.0f,0.0f};
  const int MU_OFF = PRED_*B_*2;
  const int SD_OFF = 2*PRED_*B_*2;
  for (int t = 0; t < PRED_; ++t) {
    const float nzA = noise[(t*B_ + sA*N_ + lc)*2 + (lq&1)];
    const float nzB = noise[(t*B_ + sB*N_ + lc)*2 + (lq&1)];
    // phase 0: pos snapshots (constant-indexed local arrays; R19-proven form)
    float PXsA[16], PYsA[16], PXsB[16], PYsB[16];
    #pragma unroll
    for (int a2 = 0; a2 < 16; ++a2) {
      PXsA[a2] = rlanef(POSXA, a2); PYsA[a2] = rlanef(POSYA, a2);
      PXsB[a2] = rlanef(POSXB, a2); PYsB[a2] = rlanef(POSYB, a2);
    }
    uintx4 g0A, g1A, g0B, g1B;
    MK_REFRAG(PXsA, PYsA, 0, POSXA, POSYA, g0A, g1A)
    MK_REFRAG(PXsB, PYsB, 0, POSXB, POSYB, g0B, g1B)
    // phase 1 (A then B — independent MFMAs overlap)
    uint2 epA, epB;
    PH1(slA, prevuA, epA)
    PH1(slB, prevuB, epB)
    // phase 2
    PH2(slA, epA, c4A, hfA)
    PH2(slB, epB, c4B, hfB)
    // phase 4: pool, both scenes' tile-pairs interleaved, lookahead-1
    #pragma unroll
    for (int p = 0; p < 8; ++p) {
      uintx4 n0A, n1A, n0B, n1B;
      if (p < 7) {
        MK_REFRAG(PXsA, PYsA, p+1, POSXA, POSYA, n0A, n1A)
        MK_REFRAG(PXsB, PYsB, p+1, POSXB, POSYB, n0B, n1B)
      }
      POOL_TILE(slA, cmA, 2*p,     g0A, hfA)
      POOL_TILE(slB, cmB, 2*p,     g0B, hfB)
      POOL_TILE(slA, cmA, 2*p + 1, g1A, hfA)
      POOL_TILE(slB, cmB, 2*p + 1, g1B, hfB)
      g0A = n0A; g1A = n1A; g0B = n0B; g1B = n1B;
    }
    // phase 5
    PH5(slA, sA, nzA, POSXA, POSYA, prevuA)
    PH5(slB, sB, nzB, POSXB, POSYB, prevuB)
  }
  #undef LSTM_EW
  #undef LOAD_GATE_FRAG
  #undef MK_REFRAG
  #undef POOL_TILE
  #undef PH1
  #undef PH2
  #undef PH5
  #undef ENC_STEP
  #undef MK_MASK
}

extern "C" void kernel_launch(void* const* d_in, const int* in_sizes, int n_in,
                              void* d_out, int out_size, void* d_ws, size_t ws_size,
                              hipStream_t stream) {
  (void)in_sizes; (void)n_in; (void)d_ws; (void)ws_size; (void)out_size;
  traj_ar_kernel<<<dim3(S_/SCN_), dim3(128), 0, stream>>>(
      (const float*)d_in[0],  (const float*)d_in[1],  (const int*)d_in[2],   (const float*)d_in[3],
      (const float*)d_in[4],  (const float*)d_in[5],  (const float*)d_in[6], (const float*)d_in[7],
      (const float*)d_in[8],  (const float*)d_in[9],  (const float*)d_in[10],(const float*)d_in[11],
      (const float*)d_in[12], (const float*)d_in[13], (const float*)d_in[14],(const float*)d_in[15],
      (const float*)d_in[16], (const float*)d_in[17], (const float*)d_in[18],(const float*)d_in[19],
      (float*)d_out);
}

// Round 9
// 157.089 us; speedup vs baseline: 1.2588x; 1.2588x over previous
//
#include <hip/hip_runtime.h>

#define S_    2048
#define N_    16
#define OBS_  8
#define PRED_ 12
#define B_    (S_*N_)
#define SCN_  2     // scenes (waves) per block

typedef __attribute__((ext_vector_type(8))) short short8;
typedef __attribute__((ext_vector_type(4))) float floatx4;
typedef __attribute__((ext_vector_type(4))) unsigned uintx4;
typedef unsigned short ushort_t;

__device__ __forceinline__ float sigmf(float x) { return __builtin_amdgcn_rcpf(1.0f + __expf(-x)); }
__device__ __forceinline__ float tanhx(float x) { return fmaf(-2.0f, __builtin_amdgcn_rcpf(1.0f + __expf(2.0f*x)), 1.0f); }
// f32 -> bf16 round-half-up: bits+0x8000, truncate. <=0.5 ulp like RNE (ties differ only).
__device__ __forceinline__ unsigned bfhi(float f) {
  return __builtin_bit_cast(unsigned, f) + 0x8000u;
}
__device__ __forceinline__ unsigned pack2bf(float lo, float hi) {
  return __builtin_amdgcn_perm(bfhi(hi), bfhi(lo), 0x07060302);  // [hi.b3,hi.b2,lo.b3,lo.b2]
}
__device__ __forceinline__ ushort_t f2bf1(float f) { return (ushort_t)(bfhi(f) >> 16); }
__device__ __forceinline__ float rlanef(float v, int lane) {
  return __builtin_bit_cast(float, __builtin_amdgcn_readlane(__builtin_bit_cast(int, v), lane));
}
__device__ __forceinline__ unsigned shflu(unsigned v, int src) {
  return (unsigned)__shfl((int)v, src, 64);
}
__device__ __forceinline__ unsigned shflxu(unsigned v, int m) {
  return (unsigned)__shfl_xor((int)v, m, 64);
}

// R22 = R19 (proven 70.7us, absmax 0.03125) + zero-numerics-risk edits.
// R21 post-mortem: 2 scenes/wave @ 1 wave/SIMD = 135us (VALUBusy 31%) — a
// single s_waitcnt blocks both static chains; dynamic 2-wave interleave wins.
// LESSON: never below 2 waves/SIMD here. R21 fully reverted.
// Edits vs R19 (both bit-exact):
//  1. ctx_bf read pipelining: phase1's LDS read hoisted to end-of-pool of the
//     PREVIOUS step (after all 16 ctx rows written; same-wave in-order LDS),
//     so its ~150cy latency hides under phase5. Register cvN carries it.
//     Prologue load covers t=0 (ctx_bf zero-filled at init — R13 lesson).
//  2. s_setprio(1) around the phase1+phase2 MFMA cluster (T5: helps when
//     co-resident waves sit at independent phases — ours drift, zero-barrier).
// absmax MUST stay exactly 0.03125 (tripwire; else transcription bug).
// Tripwires: VGPR > 240 / FETCH-WRITE balloon -> spill -> revert.
extern "C" __global__ __launch_bounds__(128, 2) void traj_ar_kernel(
    const float* __restrict__ traj_rel, const float* __restrict__ obs_pos,
    const int*  __restrict__ nei,       const float* __restrict__ noise,
    const float* __restrict__ eeW, const float* __restrict__ eeb,
    const float* __restrict__ eWi, const float* __restrict__ eWh, const float* __restrict__ eb,
    const float* __restrict__ diW, const float* __restrict__ dib,
    const float* __restrict__ dWi, const float* __restrict__ dWh, const float* __restrict__ db,
    const float* __restrict__ prW, const float* __restrict__ prb,
    const float* __restrict__ mW,  const float* __restrict__ mb,
    const float* __restrict__ oW,  const float* __restrict__ ob,
    float* __restrict__ out)
{
  // per-scene (wave-private) state only — nothing cross-wave
  __shared__ __align__(16) float h_s[SCN_][256];       // f32 h, phase-5 input
  __shared__ __align__(16) float ctx_s[SCN_][256];     // f32 ctx, phase-5 input
  __shared__ __align__(16) ushort_t ctx_bf[SCN_][384]; // bf16 ctx, phase-1 B input
  __shared__            unsigned sm_s[SCN_][16];

  const int tid = threadIdx.x;
  const int w  = tid >> 6;              // wave index == scene-within-block
  const int l  = tid & 63;
  const int lq = l >> 4;                // quad within wave
  const int lc = l & 15;                // col within wave (agent / unit-col)
  const int u0 = lq*4;                  // this lane's unit base
  const int s  = blockIdx.x*SCN_ + w;   // this wave's scene
  const bool hi_half = (lq >= 2);       // lanes 32..63
  // fragment-routing source lanes: this lane's b128 fragment of e/h =
  // {ep.x,ep.y} of lane esrc0 then lane esrc1 (R19-proven)
  const int esrc0 = (lq & 1)*32 + lc;
  const int esrc1 = esrc0 + 16;

  // ---- per-wave scene init (no barriers anywhere) ----
  {
    // ctx0 = 0 (FULL 192 uints — R13 lesson); h0 handled by hf=0 below
    unsigned* cz = (unsigned*)ctx_bf[w];
    cz[l] = 0; cz[64+l] = 0; cz[128+l] = 0;
  }
  // pos + prev live in REGISTERS
  float POSX = obs_pos[((OBS_-1)*B_ + s*N_ + lc)*2 + 0];
  float POSY = obs_pos[((OBS_-1)*B_ + s*N_ + lc)*2 + 1];
  unsigned prevu;
  {
    float pvx = traj_rel[((OBS_-1)*B_ + s*N_ + lc)*2 + 0];
    float pvy = traj_rel[((OBS_-1)*B_ + s*N_ + lc)*2 + 1];
    prevu = pack2bf(pvx, pvy);          // [y_bf | x_bf]
  }
  // time-invariant neighbor mask -> per-agent bitmask (wave-private)
  {
    const int a = l >> 2, nb = (l & 3)*4;
    const int4 nv = *(const int4*)&nei[(s*N_ + a)*N_ + nb];
    unsigned bits = 0;
    bits |= (nv.x > 0) ? (1u << (nb+0)) : 0u;
    bits |= (nv.y > 0) ? (1u << (nb+1)) : 0u;
    bits |= (nv.z > 0) ? (1u << (nb+2)) : 0u;
    bits |= (nv.w > 0) ? (1u << (nb+3)) : 0u;
    bits |= __shfl_xor(bits, 1, 64);
    bits |= __shfl_xor(bits, 2, 64);
    if ((l & 3) == 0) sm_s[w][a] = bits;
  }

  // pool-MLP B-fragment (32x16 bf16 weights)
  short8 bfrag;
  {
    uintx4 bw;
    #pragma unroll
    for (int p = 0; p < 4; ++p)
      bw[p] = pack2bf(mW[(8*lq + 2*p)*16 + lc], mW[(8*lq + 2*p + 1)*16 + lc]);
    bfrag = __builtin_bit_cast(short8, bw);
  }
  const float bm = mb[lc];

  // pool-rel weights for this lane's unit octet (lq&1)*8..+7
  float pWx[8], pWy[8], pB[8];
  {
    const int wu0 = (lq & 1) * 8;
    #pragma unroll
    for (int j = 0; j < 8; ++j) {
      pWx[j] = prW[wu0 + j];
      pWy[j] = prW[16 + wu0 + j];
      pB[j]  = prb[wu0 + j];
    }
  }

  // out-layer column for this lane's output lq, + bias
  float oWc[16];
  #pragma unroll
  for (int m = 0; m < 16; ++m) oWc[m] = oW[m*4 + lq];
  const float obia = ob[lq];

  // encoder embed weights for this lane's 4 units
  float ew0[4], ew1[4], ebv[4];
  #pragma unroll
  for (int r = 0; r < 4; ++r) {
    ew0[r] = eeW[u0+r]; ew1[r] = eeW[16+u0+r]; ebv[r] = eeb[u0+r];
  }

  const int row0 = (lq & 1) * 8;

  // gate A-fragment for gate g (A[row=lc][k] = W[k][g*16+lc]) + bias C by D-row unit
  #define LOAD_GATE_FRAG(A, C, Wi_, Wh_, bias_, g) {                                      \
    const float* gsrc_ = (lq & 2) ? (Wh_) : (Wi_);                                        \
    uintx4 aw_;                                                                           \
    aw_[0] = pack2bf(gsrc_[(row0+0)*64 + (g)*16 + lc], gsrc_[(row0+1)*64 + (g)*16 + lc]); \
    aw_[1] = pack2bf(gsrc_[(row0+2)*64 + (g)*16 + lc], gsrc_[(row0+3)*64 + (g)*16 + lc]); \
    aw_[2] = pack2bf(gsrc_[(row0+4)*64 + (g)*16 + lc], gsrc_[(row0+5)*64 + (g)*16 + lc]); \
    aw_[3] = pack2bf(gsrc_[(row0+6)*64 + (g)*16 + lc], gsrc_[(row0+7)*64 + (g)*16 + lc]); \
    (A) = __builtin_bit_cast(short8, aw_);                                                \
    (C)[0] = (bias_)[(g)*16 + u0 + 0]; (C)[1] = (bias_)[(g)*16 + u0 + 1];                 \
    (C)[2] = (bias_)[(g)*16 + u0 + 2]; (C)[3] = (bias_)[(g)*16 + u0 + 3];                 \
  }

  // encoder gate A-frags, all 4 gates on this wave
  short8 eA0, eA1, eA2, eA3; floatx4 eC0, eC1, eC2, eC3;
  LOAD_GATE_FRAG(eA0, eC0, eWi, eWh, eb, 0);
  LOAD_GATE_FRAG(eA1, eC1, eWi, eWh, eb, 1);
  LOAD_GATE_FRAG(eA2, eC2, eWi, eWh, eb, 2);
  LOAD_GATE_FRAG(eA3, eC3, eWi, eWh, eb, 3);

  #define LSTM_EW(r, hv) {                                                            \
    float ig = sigmf(dI[r]), fg = sigmf(dF[r]), gv = tanhx(dG[r]), og = sigmf(dO[r]); \
    c4[r] = fg*c4[r] + ig*gv;                                                         \
    hv = og * tanhx(c4[r]);                                                           \
  }

  // h fragment (B-operand rows (lq&1)*8..+8 of agent lc), carried across steps.
  uintx4 hf; hf[0]=0; hf[1]=0; hf[2]=0; hf[3]=0;

  // ---- encoder: 8 LSTM steps, zero barriers, zero LDS (regs + shfl only) ----
  floatx4 c4 = {0.0f, 0.0f, 0.0f, 0.0f};
  const float2* xr2 = (const float2*)traj_rel;
  for (int t = 0; t < OBS_; ++t) {
    float2 x = xr2[t*B_ + s*N_ + lc];
    float e0 = fmaxf(fmaf(x.y, ew1[0], fmaf(x.x, ew0[0], ebv[0])), 0.0f);
    float e1 = fmaxf(fmaf(x.y, ew1[1], fmaf(x.x, ew0[1], ebv[1])), 0.0f);
    float e2 = fmaxf(fmaf(x.y, ew1[2], fmaf(x.x, ew0[2], ebv[2])), 0.0f);
    float e3 = fmaxf(fmaf(x.y, ew1[3], fmaf(x.x, ew0[3], ebv[3])), 0.0f);
    uint2 ep; ep.x = pack2bf(e0, e1); ep.y = pack2bf(e2, e3);
    uintx4 eu;
    eu[0] = shflu(ep.x, esrc0); eu[1] = shflu(ep.y, esrc0);
    eu[2] = shflu(ep.x, esrc1); eu[3] = shflu(ep.y, esrc1);
    uintx4 bu = (lq < 2) ? eu : hf;     // hi lanes: h of PREVIOUS step
    short8 bfr = __builtin_bit_cast(short8, bu);
    floatx4 dI = __builtin_amdgcn_mfma_f32_16x16x32_bf16(eA0, bfr, eC0, 0, 0, 0);
    floatx4 dF = __builtin_amdgcn_mfma_f32_16x16x32_bf16(eA1, bfr, eC1, 0, 0, 0);
    floatx4 dG = __builtin_amdgcn_mfma_f32_16x16x32_bf16(eA2, bfr, eC2, 0, 0, 0);
    floatx4 dO = __builtin_amdgcn_mfma_f32_16x16x32_bf16(eA3, bfr, eC3, 0, 0, 0);
    float h40, h41, h42, h43;
    LSTM_EW(0, h40); LSTM_EW(1, h41); LSTM_EW(2, h42); LSTM_EW(3, h43);
    uint2 hp2; hp2.x = pack2bf(h40, h41); hp2.y = pack2bf(h42, h43);
    hf[0] = shflu(hp2.x, esrc0); hf[1] = shflu(hp2.y, esrc0);
    hf[2] = shflu(hp2.x, esrc1); hf[3] = shflu(hp2.y, esrc1);
  }

  // decoder gate A-frags (separate live range from encoder's)
  short8 dA0, dA1, dA2, dA3; floatx4 dC0, dC1, dC2, dC3;
  LOAD_GATE_FRAG(dA0, dC0, dWi, dWh, db, 0);
  LOAD_GATE_FRAG(dA1, dC1, dWi, dWh, db, 1);
  LOAD_GATE_FRAG(dA2, dC2, dWi, dWh, db, 2);
  LOAD_GATE_FRAG(dA3, dC3, dWi, dWh, db, 3);

  // dec-in A-fragment: kk 0..15 = ctx rows, 16,17 = prev rows, 18..31 zero-pad
  short8 diA; floatx4 diC;
  {
    uintx4 aw; aw[0]=0; aw[1]=0; aw[2]=0; aw[3]=0;
    if (lq < 2) {
      const int r0 = lq*8;
      #pragma unroll
      for (int p = 0; p < 4; ++p)
        aw[p] = pack2bf(diW[(r0+2*p)*16 + lc], diW[(r0+2*p+1)*16 + lc]);
    } else if (lq == 2) {
      aw[0] = pack2bf(diW[16*16 + lc], diW[17*16 + lc]);
    }
    diA = __builtin_bit_cast(short8, aw);
    #pragma unroll
    for (int r = 0; r < 4; ++r) diC[r] = dib[u0 + r];
  }

  // pool C-operands, all 16 target agents, mask baked (time-invariant).
  floatx4 cm[16];
  #pragma unroll
  for (int tt = 0; tt < 16; ++tt) {
    const unsigned mi = sm_s[w][tt];
    #pragma unroll
    for (int r = 0; r < 4; ++r)
      cm[tt][r] = ((mi >> (u0 + r)) & 1u) ? bm : -1e9f;
  }

  // R19-identical refrag: lanes<32 re(2pp), lanes>=32 re(2pp+1); F1 routed
  // down via proven shfl_xor(32). Bit-identical fma nesting + pack pairing.
  #define MK_REFRAG(pp, F0, F1) {                                           \
    const int t0_ = 2*(pp), t1_ = 2*(pp)+1;                                 \
    float rx0_ = PXs[t0_] - POSX, ry0_ = PYs[t0_] - POSY;                   \
    float rx1_ = PXs[t1_] - POSX, ry1_ = PYs[t1_] - POSY;                   \
    float rx_ = hi_half ? rx1_ : rx0_;                                      \
    float ry_ = hi_half ? ry1_ : ry0_;                                      \
    float rr_[8];                                                           \
    _Pragma("unroll")                                                       \
    for (int j = 0; j < 8; ++j)                                             \
      rr_[j] = fmaxf(fmaf(ry_, pWy[j], fmaf(rx_, pWx[j], pB[j])), 0.0f);    \
    (F0)[0] = pack2bf(rr_[0], rr_[1]);                                      \
    (F0)[1] = pack2bf(rr_[2], rr_[3]);                                      \
    (F0)[2] = pack2bf(rr_[4], rr_[5]);                                      \
    (F0)[3] = pack2bf(rr_[6], rr_[7]);                                      \
    (F1)[0] = shflxu((F0)[0], 32);                                          \
    (F1)[1] = shflxu((F0)[1], 32);                                          \
    (F1)[2] = shflxu((F0)[2], 32);                                          \
    (F1)[3] = shflxu((F0)[3], 32);                                          \
  }

  // R19-identical pool tile (proven shfl_xor reduce, writer lq == tt&3)
  #define POOL_TILE(tt, FRAG) {                                             \
    short8 a_ = hi_half ? __builtin_bit_cast(short8, hf)                    \
                        : __builtin_bit_cast(short8, FRAG);                 \
    floatx4 d_ = __builtin_amdgcn_mfma_f32_16x16x32_bf16(a_, bfrag, cm[tt], 0, 0, 0); \
    float pm_ = fmaxf(fmaxf(d_[0], d_[1]), fmaxf(d_[2], d_[3]));            \
    pm_ = fmaxf(pm_, __shfl_xor(pm_, 16, 64));                              \
    pm_ = fmaxf(pm_, __shfl_xor(pm_, 32, 64));                              \
    if (lq == ((tt) & 3)) {                                                 \
      float cvv_ = fmaxf(pm_, 0.0f);                                        \
      ctx_s[w][(tt)*16 + lc] = cvv_;                                        \
      ctx_bf[w][(tt)*24 + lc] = f2bf1(cvv_);                                \
    }                                                                       \
  }

  // ---- decoder: 12 autoregressive steps, ZERO barriers ----
  c4 = (floatx4){0.0f, 0.0f, 0.0f, 0.0f};
  const int MU_OFF = PRED_*B_*2;
  const int SD_OFF = 2*PRED_*B_*2;
  // R22 edit 1: prologue ctx_bf load (step-0 ctx = zeros, written above by
  // THIS wave — same-wave in-order LDS). Carried across iterations in cvN.
  short8 cvN = *(const short8*)&ctx_bf[w][lc*24 + (lq&1)*8];
  for (int t = 0; t < PRED_; ++t) {
    // early noise load: consumed in phase 5
    const float nz = noise[(t*B_ + s*N_ + lc)*2 + (lq&1)];
    // phase 0: all-agent pos snapshot -> uniform regs (32 v_readlane)
    float PXs[16], PYs[16];
    #pragma unroll
    for (int a2 = 0; a2 < 16; ++a2) {
      PXs[a2] = rlanef(POSX, a2);
      PYs[a2] = rlanef(POSY, a2);
    }
    // pair-0 re fragments hoisted: their shuffles overlap phases 1-2
    uintx4 g0, g1;
    MK_REFRAG(0, g0, g1);
    // phase 1: e = relu([ctx|prev] @ dec_in_W + b) via MFMA.
    // ctx B-rows come from cvN (preloaded at end of previous step's pool).
    uint2 ep;
    {
      uintx4 pz; pz[0] = prevu; pz[1]=0; pz[2]=0; pz[3]=0;
      short8 pv = __builtin_bit_cast(short8, pz);
      short8 zz = {0,0,0,0,0,0,0,0};
      short8 bf1 = (lq < 2) ? cvN : ((lq == 2) ? pv : zz);
      __builtin_amdgcn_s_setprio(1);               // R22 edit 2
      floatx4 d = __builtin_amdgcn_mfma_f32_16x16x32_bf16(diA, bf1, diC, 0, 0, 0);
      __builtin_amdgcn_s_setprio(0);
      ep.x = pack2bf(fmaxf(d[0],0.0f), fmaxf(d[1],0.0f));
      ep.y = pack2bf(fmaxf(d[2],0.0f), fmaxf(d[3],0.0f));
    }
    // phase 2: e fragment via 4 shfl; 4 gate MFMAs + elementwise;
    // h -> h_s (phase 5) + new hf fragment (pool & next step)
    {
      uintx4 eu;
      eu[0] = shflu(ep.x, esrc0); eu[1] = shflu(ep.y, esrc0);
      eu[2] = shflu(ep.x, esrc1); eu[3] = shflu(ep.y, esrc1);
      uintx4 bu = (lq < 2) ? eu : hf;   // hi lanes: h of PREVIOUS step
      short8 bfr = __builtin_bit_cast(short8, bu);
      __builtin_amdgcn_s_setprio(1);               // R22 edit 2
      floatx4 dI = __builtin_amdgcn_mfma_f32_16x16x32_bf16(dA0, bfr, dC0, 0, 0, 0);
      floatx4 dF = __builtin_amdgcn_mfma_f32_16x16x32_bf16(dA1, bfr, dC1, 0, 0, 0);
      floatx4 dG = __builtin_amdgcn_mfma_f32_16x16x32_bf16(dA2, bfr, dC2, 0, 0, 0);
      floatx4 dO = __builtin_amdgcn_mfma_f32_16x16x32_bf16(dA3, bfr, dC3, 0, 0, 0);
      __builtin_amdgcn_s_setprio(0);
      float h40, h41, h42, h43;
      LSTM_EW(0, h40); LSTM_EW(1, h41); LSTM_EW(2, h42); LSTM_EW(3, h43);
      uint2 hp2; hp2.x = pack2bf(h40, h41); hp2.y = pack2bf(h42, h43);
      hf[0] = shflu(hp2.x, esrc0); hf[1] = shflu(hp2.y, esrc0);
      hf[2] = shflu(hp2.x, esrc1); hf[3] = shflu(hp2.y, esrc1);
      floatx4 hv4; hv4[0]=h40; hv4[1]=h41; hv4[2]=h42; hv4[3]=h43;
      *(floatx4*)&h_s[w][lc*16 + u0] = hv4;
    }
    // phase 4: masked max-pool, 8 tile-pairs, lookahead-1 pipeline
    {
      #pragma unroll
      for (int p = 0; p < 8; ++p) {
        uintx4 n0, n1;
        if (p < 7) MK_REFRAG(p+1, n0, n1);
        POOL_TILE(2*p,     g0);
        POOL_TILE(2*p + 1, g1);
        g0 = n0; g1 = n1;
      }
    }
    // R22 edit 1: issue NEXT step's ctx_bf read now — all 16 ctx rows were
    // written by the pool above (same-wave in-order LDS); the ~150cy latency
    // hides under phase 5's independent work.
    cvN = *(const short8*)&ctx_bf[w][lc*24 + (lq&1)*8];
    // phase 5: o4 = (h+ctx)@out_W + b; pr computed in ALL lanes (stores
    // guarded); pos/prev advance via shuffle broadcasts
    {
      float acc = obia;
      const floatx4* hp4 = (const floatx4*)&h_s[w][lc*16];
      const floatx4* cx4 = (const floatx4*)&ctx_s[w][lc*16];
      #pragma unroll
      for (int mm = 0; mm < 4; ++mm) {
        floatx4 hv = hp4[mm];
        floatx4 cv = cx4[mm];
        #pragma unroll
        for (int r = 0; r < 4; ++r)
          acc = fmaf(hv[r]+cv[r], oWc[mm*4+r], acc);
      }
      float sc = __shfl_down(acc, 32, 64);   // lq<2 grabs o4[lq+2]
      float mu = acc;
      float scale = fminf(fmaxf(sc, -9.0f), 4.0f);
      float sd = __expf(scale);
      float pr = fmaf(sd, nz, mu);
      if (lq < 2) {
        int o = (t*B_ + s*N_ + lc)*2 + lq;
        out[o]          = pr;
        out[MU_OFF + o] = mu;
        out[SD_OFF + o] = sd;
      }
      float prx = __shfl(pr, lc, 64);        // agent lc's x-delta (lane lc)
      float pry = __shfl(pr, 16 + lc, 64);   // agent lc's y-delta (lane 16+lc)
      POSX += prx;
      POSY += pry;
      prevu = pack2bf(prx, pry);             // same bits as before
    }
  }
  #undef LSTM_EW
  #undef LOAD_GATE_FRAG
  #undef MK_REFRAG
  #undef POOL_TILE
}

extern "C" void kernel_launch(void* const* d_in, const int* in_sizes, int n_in,
                              void* d_out, int out_size, void* d_ws, size_t ws_size,
                              hipStream_t stream) {
  (void)in_sizes; (void)n_in; (void)d_ws; (void)ws_size; (void)out_size;
  traj_ar_kernel<<<dim3(S_/SCN_), dim3(128), 0, stream>>>(
      (const float*)d_in[0],  (const float*)d_in[1],  (const int*)d_in[2],   (const float*)d_in[3],
      (const float*)d_in[4],  (const float*)d_in[5],  (const float*)d_in[6], (const float*)d_in[7],
      (const float*)d_in[8],  (const float*)d_in[9],  (const float*)d_in[10],(const float*)d_in[11],
      (const float*)d_in[12], (const float*)d_in[13], (const float*)d_in[14],(const float*)d_in[15],
      (const float*)d_in[16], (const float*)d_in[17], (const float*)d_in[18],(const float*)d_in[19],
      (float*)d_out);
}